// Round 15
// baseline (108.666 us; speedup 1.0000x reference)
//
#include <hip/hip_runtime.h>
#include <stdint.h>

#define NB 16
#define NN 2048
#define ND 128
#define NH 32
#define NS (NB*NN)

typedef __attribute__((ext_vector_type(8))) short bf16x8;
typedef __attribute__((ext_vector_type(4))) float f32x4;
typedef __attribute__((ext_vector_type(16))) float f32x16;
typedef __attribute__((ext_vector_type(2))) int i32x2;

__device__ __forceinline__ unsigned short f2bf(float f){
  union { float f; unsigned int u; } v; v.f = f;
  unsigned int r = v.u + 0x7fffu + ((v.u >> 16) & 1u);
  return (unsigned short)(r >> 16);
}
__device__ __forceinline__ float bf2f(unsigned short u){
  union { unsigned int u; float f; } v; v.u = ((unsigned int)u) << 16;
  return v.f;
}
// raw 2^x (Q is pre-scaled by log2e, so exp(S) == exp2(S'))
__device__ __forceinline__ float fexp2(float x){
  float r; asm("v_exp_f32 %0, %1" : "=v"(r) : "v"(x)); return r;
}
// v_permlane32_swap_b32: after pswap(x,y): x = {x.lo, y.lo}, y = {x.hi, y.hi}
__device__ __forceinline__ void pswap(unsigned int &x, unsigned int &y){
#if __has_builtin(__builtin_amdgcn_permlane32_swap)
  i32x2 r = __builtin_amdgcn_permlane32_swap((int)x, (int)y, false, false);
  x = (unsigned int)r[0]; y = (unsigned int)r[1];
#else
  unsigned int sx = (unsigned int)__shfl_xor((int)x, 32, 64);
  unsigned int sy = (unsigned int)__shfl_xor((int)y, 32, 64);
  bool hi = ((threadIdx.x & 63) >> 5) != 0;
  unsigned int nx = hi ? sy : x;
  unsigned int ny = hi ? y  : sx;
  x = nx; y = ny;
#endif
}

// ---------------- k_prep: fp32 weights -> bf16 ----------------
__global__ __launch_bounds__(256) void k_prep(const float* wq, const float* wk, const float* wv, const float* wl,
                                              unsigned short* oq, unsigned short* ok, unsigned short* ov, unsigned short* ol){
  int i = blockIdx.x*256 + threadIdx.x;
  if (i < 4096) oq[i] = f2bf(wq[i]);
  else if (i < 8192) ok[i-4096] = f2bf(wk[i-4096]);
  else if (i < 24576) ov[i-8192] = f2bf(wv[i-8192]);
  else if (i < 40960) ol[i-24576] = f2bf(wl[i-24576]);
}

// ---------------- k_qkv: Q (scaled by log2e), K (S x 32), V (S x 128) in bf16 ----------------
__global__ __launch_bounds__(256) void k_qkv(const float* f, const unsigned short* wbq, const unsigned short* wbk,
                                             const unsigned short* wbv, const float* bq, const float* bk, const float* bv,
                                             unsigned short* Qb, unsigned short* Kb, unsigned short* Vb){
  int tid = threadIdx.x, wave = tid>>6, lane = tid&63, lr = lane&15, lg = lane>>4;
  long r0 = (long)blockIdx.x*64 + wave*16;
  bf16x8 a[4];
  const float4* frow4 = (const float4*)(f + (r0 + lr)*ND);
  #pragma unroll
  for (int ks=0; ks<4; ks++){
    int base = ks*8 + lg*2;
    float4 x0 = frow4[base], x1 = frow4[base+1];
    bf16x8 t;
    t[0]=(short)f2bf(x0.x); t[1]=(short)f2bf(x0.y); t[2]=(short)f2bf(x0.z); t[3]=(short)f2bf(x0.w);
    t[4]=(short)f2bf(x1.x); t[5]=(short)f2bf(x1.y); t[6]=(short)f2bf(x1.z); t[7]=(short)f2bf(x1.w);
    a[ks] = t;
  }
  #pragma unroll
  for (int cs=0; cs<12; cs++){
    const unsigned short* wsrc; const float* bsrc; int cl;
    if (cs<2){ wsrc=wbq; bsrc=bq; cl=cs*16; }
    else if (cs<4){ wsrc=wbk; bsrc=bk; cl=(cs-2)*16; }
    else { wsrc=wbv; bsrc=bv; cl=(cs-4)*16; }
    f32x4 acc = {0.f,0.f,0.f,0.f};
    #pragma unroll
    for (int ks=0;ks<4;ks++){
      bf16x8 b = *(const bf16x8*)(wsrc + (cl+lr)*ND + ks*32 + lg*8);
      acc = __builtin_amdgcn_mfma_f32_16x16x32_bf16(a[ks], b, acc, 0, 0, 0);
    }
    float bias = bsrc[cl + lr];
    #pragma unroll
    for (int r=0;r<4;r++){
      float v = acc[r] + bias;
      if (cs<2) v *= 1.4426950408889634f;   // fold log2(e) into Q
      long row = r0 + lg*4 + r;
      if (cs<2) Qb[row*NH + cl+lr] = f2bf(v);
      else if (cs<4) Kb[row*NH + cl+lr] = f2bf(v);
      else Vb[row*ND + cl+lr] = f2bf(v);
    }
  }
}

// ---------------- k_csv (R9-proven, verbatim): colsum + V' transpose/scale ----------------
// VT has 160 rows/batch: rows 0-127 = V^T * w (bf16), row 128 = w (bf16), rows 129-159 = 0.
__global__ __launch_bounds__(256) void k_csv(const unsigned short* Qb, const unsigned short* Kb,
                                             const unsigned short* Vb, unsigned short* VT){
  __shared__ unsigned short tr[128][65];
  __shared__ float wsh[64];
  __shared__ __align__(16) unsigned char qs[3][4096];
  int tid=threadIdx.x, wave=tid>>6, lane=tid&63, lr=lane&15, lg=lane>>4;
  int wg = (blockIdx.x & 7)*64 + (blockIdx.x >> 3);   // XCD-chunked swizzle (512 % 8 == 0)
  int b = wg >> 5;
  int m0 = (wg & 31)*64;
  const unsigned short* Qbb = Qb + (long)b*NN*NH;
  const unsigned short* Kbb = Kb + (long)b*NN*NH;
  const unsigned short* Vbb = Vb + ((long)b*NN + m0)*ND;

  auto stageQ = [&](int buf, int n0){
    int row = wave*16 + (lane>>2);      // 0..63
    int blk = lane & 3;
    int scol = (blk ^ ((row>>1)&3))*8;  // pre-swizzled source column (elems)
    __builtin_amdgcn_global_load_lds(
      (const __attribute__((address_space(1))) unsigned int*)(Qbb + (long)(n0+row)*NH + scol),
      (__attribute__((address_space(3))) unsigned int*)(&qs[buf][wave*1024]), 16, 0, 0);
  };

  // V loads early (consumed after the loop); drained by the first wait
  bf16x8 vreg[4];
  #pragma unroll
  for (int it=0; it<4; it++){
    int i = it*256 + tid;
    int r = i >> 4, c8 = (i & 15)*8;
    vreg[it] = *(const bf16x8*)(Vbb + r*ND + c8);
  }
  bf16x8 kf = *(const bf16x8*)(Kbb + (m0 + wave*16 + lr)*NH + lg*8);
  stageQ(0, 0);
  stageQ(1, 64);

  float csum = 0.f;
  int qrd = (lg ^ ((lr>>1)&3)) << 4;    // read blk offset (u-invariant)
  int qc = 0, qsn = 2;
  for (int it = 0; it < 32; ++it){
    if (it < 31) asm volatile("s_waitcnt vmcnt(1)" ::: "memory");
    else         asm volatile("s_waitcnt vmcnt(0)" ::: "memory");
    __builtin_amdgcn_s_barrier();
    if (it + 2 < 32) stageQ(qsn, (it+2)*64);
    asm volatile("" ::: "memory");
    #pragma unroll
    for (int u=0; u<4; u++){
      int r = u*16 + lr;
      bf16x8 qf = *(const bf16x8*)(&qs[qc][r*64 + qrd]);
      f32x4 c = {0.f,0.f,0.f,0.f};
      c = __builtin_amdgcn_mfma_f32_16x16x32_bf16(qf, kf, c, 0, 0, 0);
      csum += fexp2(c[0]) + fexp2(c[1]) + fexp2(c[2]) + fexp2(c[3]);
    }
    qc = (qc==2)?0:qc+1;
    qsn = (qsn==2)?0:qsn+1;
  }
  csum += __shfl_xor(csum, 16, 64);
  csum += __shfl_xor(csum, 32, 64);
  #pragma unroll
  for (int it=0; it<4; it++){
    int i = it*256 + tid;
    int r = i >> 4, c8 = (i & 15)*8;
    #pragma unroll
    for (int j=0;j<8;j++) tr[c8+j][r] = (unsigned short)vreg[it][j];
  }
  if (lg == 0) wsh[wave*16 + lr] = 1.f / csum;
  __syncthreads();
  unsigned short* VTb = VT + (long)b*160*NN;
  #pragma unroll
  for (int it=0; it<9; it++){
    int i = it*256 + tid;
    int e = i >> 4, m4 = (i & 15)*4;
    ushort4 o;
    if (e < 128){
      o.x = f2bf(bf2f(tr[e][m4+0]) * wsh[m4+0]);
      o.y = f2bf(bf2f(tr[e][m4+1]) * wsh[m4+1]);
      o.z = f2bf(bf2f(tr[e][m4+2]) * wsh[m4+2]);
      o.w = f2bf(bf2f(tr[e][m4+3]) * wsh[m4+3]);
    } else if (e == 128){
      o.x = f2bf(wsh[m4+0]); o.y = f2bf(wsh[m4+1]);
      o.z = f2bf(wsh[m4+2]); o.w = f2bf(wsh[m4+3]);
    } else { o.x = o.y = o.z = o.w = 0; }
    *(ushort4*)(VTb + (long)e*NN + m0 + m4) = o;
  }
  // zero-pad rows 144..159
  {
    int e = 144 + (tid >> 4), m4 = (tid & 15)*4;
    ushort4 z; z.x = z.y = z.z = z.w = 0;
    *(ushort4*)(VTb + (long)e*NN + m0 + m4) = z;
  }
}

// ---------------- k_pv: partial (E @ V', E @ w) over HALF the m-range ----------------
// R14 lean loop + K register-prefetch one iter ahead (R7-proven pattern).
// Queue ledger: prologue [qf2, K0_4, V0_5]=11. Iter it: barrier -> K(it+1)_4 -> V(it+1)_5
// -> vmcnt(9) leaves K(it+1)+V(it+1), drains K(it)/V(it)/qf. Last iter vmcnt(0).
// NO launch_bounds min-waves hint (spills corrupt counted vmcnt — R10-R12 lesson).
__global__ __launch_bounds__(256) void k_pv(const unsigned short* Qb, const unsigned short* Kb,
                                            const unsigned short* VT,
                                            unsigned short* pnum, float* pden){
  __shared__ __align__(16) unsigned char vts[2][20480];
  int tid=threadIdx.x, wave=tid>>6, lane=tid&63;
  int l31 = lane & 31, H = lane >> 5;
  int wg = (blockIdx.x & 7)*64 + (blockIdx.x >> 3);   // XCD-chunked swizzle (512 % 8 == 0)
  int half = wg & 1;
  int bq = wg >> 1;
  int b = bq >> 4;
  int q0 = (bq & 15)*128 + wave*32;
  int mbase = half*1024;
  const int NT = 16;
  const unsigned short* Qbb = Qb + (long)b*NN*NH;
  const unsigned short* Kbb = Kb + (long)b*NN*NH;
  const unsigned short* VTb = VT + (long)b*160*NN;

  auto stageV = [&](int buf, int m0c){
    #pragma unroll
    for (int t=0;t<5;t++){
      int i = wave*5 + t;                 // 0..19 row-groups of 8 -> 160 rows
      int e = i*8 + (lane>>3);
      int sblk = (lane&7) ^ (e&7);        // pre-swizzled source block
      __builtin_amdgcn_global_load_lds(
        (const __attribute__((address_space(1))) unsigned int*)(VTb + (long)e*NN + m0c + sblk*8),
        (__attribute__((address_space(3))) unsigned int*)(&vts[buf][i*1024]), 16, 0, 0);
    }
  };

  // qf loads FIRST (oldest in queue)
  bf16x8 qf0 = *(const bf16x8*)(Qbb + (long)(q0 + l31)*NH + 8*H);
  bf16x8 qf1 = *(const bf16x8*)(Qbb + (long)(q0 + l31)*NH + 16 + 8*H);
  asm volatile("" ::: "memory");
  // K(0) regs
  bf16x8 k00 = *(const bf16x8*)(Kbb + (long)(mbase + l31)*NH + 8*H);
  bf16x8 k01 = *(const bf16x8*)(Kbb + (long)(mbase + l31)*NH + 16 + 8*H);
  bf16x8 k10 = *(const bf16x8*)(Kbb + (long)(mbase + 32 + l31)*NH + 8*H);
  bf16x8 k11 = *(const bf16x8*)(Kbb + (long)(mbase + 32 + l31)*NH + 16 + 8*H);
  asm volatile("" ::: "memory");
  stageV(0, mbase);                       // V(0)
  asm volatile("" ::: "memory");

  f32x16 acc[5];
  #pragma unroll
  for (int c=0;c<5;c++)
    #pragma unroll
    for (int r=0;r<16;r++) acc[c][r] = 0.f;

  union U { unsigned int u[4]; bf16x8 v; };

  int cur = 0;
  for (int it = 0; it < NT; ++it){
    __builtin_amdgcn_s_barrier();          // all waves done reading vts[cur^1]
    bool pf = (it + 1 < NT);
    bf16x8 n00, n01, n10, n11;
    if (pf){
      // K(it+1) prefetch — issued BEFORE stageV(it+1), so it's older in the vm queue
      long mb = mbase + (long)(it+1)*64;
      n00 = *(const bf16x8*)(Kbb + (mb + l31)*NH + 8*H);
      n01 = *(const bf16x8*)(Kbb + (mb + l31)*NH + 16 + 8*H);
      n10 = *(const bf16x8*)(Kbb + (mb + 32 + l31)*NH + 8*H);
      n11 = *(const bf16x8*)(Kbb + (mb + 32 + l31)*NH + 16 + 8*H);
    }
    asm volatile("" ::: "memory");
    if (pf) stageV(cur^1, mbase + (it+1)*64);
    asm volatile("" ::: "memory");
    if (pf) asm volatile("s_waitcnt vmcnt(9)" ::: "memory");  // drains K(it)+V(it)+(qf)
    else    asm volatile("s_waitcnt vmcnt(0)" ::: "memory");
    __builtin_amdgcn_sched_barrier(0);
    const unsigned char* vcur = &vts[cur][0];

    #pragma unroll
    for (int t=0;t<2;t++){
      // score: S^T[m][q], m-subtile t (32 m-rows)
      f32x16 s;
      #pragma unroll
      for (int r=0;r<16;r++) s[r] = 0.f;
      s = __builtin_amdgcn_mfma_f32_32x32x16_bf16(t ? k10 : k00, qf0, s, 0, 0, 0);
      s = __builtin_amdgcn_mfma_f32_32x32x16_bf16(t ? k11 : k01, qf1, s, 0, 0, 0);
      #pragma unroll
      for (int r=0;r<16;r++) s[r] = fexp2(s[r]);
      // pack to bf16 pairs; cross-half exchange via permlane32_swap (pure VALU)
      unsigned int pk[8];
      #pragma unroll
      for (int p=0;p<8;p++)
        asm("v_cvt_pk_bf16_f32 %0, %1, %2" : "=v"(pk[p]) : "v"(s[2*p]), "v"(s[2*p+1]));
      pswap(pk[0], pk[2]);
      pswap(pk[1], pk[3]);
      pswap(pk[4], pk[6]);
      pswap(pk[5], pk[7]);
      // PV: acc[c] += E(32q x 16m) @ V'(16m x 32e), 2 k-steps x 5 e-tiles (c=4 -> den col 128)
      __builtin_amdgcn_s_setprio(1);
      #pragma unroll
      for (int ksl=0; ksl<2; ksl++){
        int KS = 2*t + ksl;
        U fa;
        #pragma unroll
        for (int i2=0;i2<4;i2++) fa.u[i2] = pk[ksl*4 + i2];
        #pragma unroll
        for (int c=0;c<5;c++){
          int e = c*32 + l31;
          bf16x8 vb = *(const bf16x8*)(vcur + (e<<7) + (((2*KS + H) ^ (e&7))<<4));
          acc[c] = __builtin_amdgcn_mfma_f32_32x32x16_bf16(fa.v, vb, acc[c], 0, 0, 0);
        }
      }
      __builtin_amdgcn_s_setprio(0);
    }
    if (pf){ k00 = n00; k01 = n01; k10 = n10; k11 = n11; }
    cur ^= 1;
  }
  // write partials: numerator bf16; denominator f32 from acc[4] (V' col 128 = w, at l31==0)
  unsigned short* pn = pnum + (long)half*NS*ND + (long)b*NN*ND;
  float* pd = pden + (long)half*NS + (long)b*NN;
  #pragma unroll
  for (int r=0;r<16;r++){
    int rho = (r&3) + 8*(r>>2) + 4*H;
    long q = q0 + rho;
    #pragma unroll
    for (int c=0;c<4;c++)
      pn[q*ND + c*32 + l31] = f2bf(acc[c][r]);
    if (l31 == 0) pd[q] = acc[4][r];
  }
}

// ---------------- k_lin (R9-proven): fsa = (pn0+pn1)/(pd0+pd1) in-reg; y = (f - fsa) @ w_l^T + b_l ----------------
__global__ __launch_bounds__(256) void k_lin(const float* f, const unsigned short* pnum, const float* pden,
                                             const unsigned short* wbl, const float* bl,
                                             unsigned short* fsab, unsigned short* ybuf, float* part){
  __shared__ float psum[4][128], psq[4][128];
  int tid=threadIdx.x, wave=tid>>6, lane=tid&63, lr=lane&15, lg=lane>>4;
  long r0 = (long)blockIdx.x*64 + wave*16;
  long row = r0 + lr;
  float rinv = 1.f / (pden[row] + pden[NS + row]);
  bf16x8 a[4];
  {
    const float4* fr4 = (const float4*)(f + row*ND);
    const unsigned short* p0 = pnum + row*ND;
    const unsigned short* p1 = pnum + (long)NS*ND + row*ND;
    #pragma unroll
    for (int ks=0;ks<4;ks++){
      int c8 = ks*4 + lg;
      float4 x0 = fr4[c8*2], x1 = fr4[c8*2+1];
      bf16x8 v0 = *(const bf16x8*)(p0 + c8*8);
      bf16x8 v1 = *(const bf16x8*)(p1 + c8*8);
      float xf[8] = {x0.x,x0.y,x0.z,x0.w,x1.x,x1.y,x1.z,x1.w};
      bf16x8 t, fs;
      #pragma unroll
      for (int j=0;j<8;j++){
        float sa = (bf2f((unsigned short)v0[j]) + bf2f((unsigned short)v1[j])) * rinv;
        fs[j] = (short)f2bf(sa);
        t[j] = (short)f2bf(xf[j] - bf2f((unsigned short)fs[j]));
      }
      a[ks] = t;
      *(bf16x8*)(fsab + row*ND + c8*8) = fs;
    }
  }
  #pragma unroll
  for (int cs=0;cs<8;cs++){
    f32x4 acc = {0.f,0.f,0.f,0.f};
    #pragma unroll
    for (int ks=0;ks<4;ks++){
      bf16x8 bfr = *(const bf16x8*)(wbl + (cs*16+lr)*ND + ks*32 + lg*8);
      acc = __builtin_amdgcn_mfma_f32_16x16x32_bf16(a[ks], bfr, acc, 0, 0, 0);
    }
    float bias = bl[cs*16+lr];
    float l1=0.f, l2=0.f;
    #pragma unroll
    for (int r=0;r<4;r++){
      float y = acc[r] + bias;
      ybuf[(r0 + lg*4 + r)*ND + cs*16 + lr] = f2bf(y);
      l1 += y; l2 += y*y;
    }
    l1 += __shfl_xor(l1,16,64); l1 += __shfl_xor(l1,32,64);
    l2 += __shfl_xor(l2,16,64); l2 += __shfl_xor(l2,32,64);
    if (lg==0){ psum[wave][cs*16+lr] = l1; psq[wave][cs*16+lr] = l2; }
  }
  __syncthreads();
  if (tid < 128){
    float t1 = psum[0][tid]+psum[1][tid]+psum[2][tid]+psum[3][tid];
    float t2 = psq[0][tid]+psq[1][tid]+psq[2][tid]+psq[3][tid];
    part[tid*512 + blockIdx.x] = t1;
    part[65536 + tid*512 + blockIdx.x] = t2;
  }
}

// ---------------- k_bnred: per-channel reduction -> BN scale/shift ----------------
__global__ __launch_bounds__(64) void k_bnred(const float* part, const float* gamma, const float* beta, float* bnstat){
  int c = blockIdx.x, t = threadIdx.x;
  float s=0.f, q=0.f;
  for (int i=t; i<512; i+=64){ s += part[c*512+i]; q += part[65536 + c*512+i]; }
  #pragma unroll
  for (int m=1; m<64; m<<=1){ s += __shfl_xor(s,m,64); q += __shfl_xor(q,m,64); }
  if (t==0){
    float mean = s * (1.f/(float)NS);
    float var  = q * (1.f/(float)NS) - mean*mean;
    float rstd = rsqrtf(var + 1e-5f);
    float sc = gamma[c]*rstd;
    bnstat[c] = sc;
    bnstat[128+c] = beta[c] - mean*sc;
  }
}

// ---------------- k_final: out = relu(y*scale + shift) + fsa ----------------
__global__ __launch_bounds__(256) void k_final(const unsigned short* ybuf, const unsigned short* fsab, const float* bnstat,
                                               float* out){
  long i0 = ((long)blockIdx.x*256 + threadIdx.x)*8;
  int c0 = (int)(i0 & (ND-1));
  bf16x8 yv = *(const bf16x8*)(ybuf + i0);
  bf16x8 fv = *(const bf16x8*)(fsab + i0);
  f32x4 o0, o1;
  #pragma unroll
  for (int j=0;j<8;j++){
    int c = c0 + j;
    float v = bf2f((unsigned short)yv[j]) * bnstat[c] + bnstat[128+c];
    v = v > 0.f ? v : 0.f;
    float r = v + bf2f((unsigned short)fv[j]);
    if (j<4) o0[j] = r; else o1[j-4] = r;
  }
  *(f32x4*)(out + i0) = o0;
  *(f32x4*)(out + i0 + 4) = o1;
}

extern "C" void kernel_launch(void* const* d_in, const int* in_sizes, int n_in,
                              void* d_out, int out_size, void* d_ws, size_t ws_size,
                              hipStream_t stream){
  const float* f_in  = (const float*)d_in[0];
  const float* w_q   = (const float*)d_in[1];
  const float* b_q   = (const float*)d_in[2];
  const float* w_k   = (const float*)d_in[3];
  const float* b_k   = (const float*)d_in[4];
  const float* w_v   = (const float*)d_in[5];
  const float* b_v   = (const float*)d_in[6];
  const float* w_l   = (const float*)d_in[7];
  const float* b_l   = (const float*)d_in[8];
  const float* gamma = (const float*)d_in[9];
  const float* beta  = (const float*)d_in[10];
  float* out = (float*)d_out;
  char* ws = (char*)d_ws;

  // ws layout (peak ~40.2 MB; overlays annotated by liveness)
  unsigned short* wbq = (unsigned short*)(ws + 0);
  unsigned short* wbk = (unsigned short*)(ws + 8192);
  unsigned short* wbv = (unsigned short*)(ws + 16384);
  unsigned short* wbl = (unsigned short*)(ws + 49152);
  unsigned short* Qb  = (unsigned short*)(ws + 81920);     // 2 MB     [k_qkv -> k_pv]
  float*          part= (float*)(ws + 81920);              // 0.52 MB  [k_lin -> k_bnred] (over dead Qb)
  unsigned short* Kb  = (unsigned short*)(ws + 2179072);   // 2 MB     [k_qkv -> k_pv]
  unsigned short* VT  = (unsigned short*)(ws + 4276224);   // 10.49 MB [k_csv -> k_pv] (160 rows/batch)
  unsigned short* ybuf= (unsigned short*)(ws + 4276224);   // 8.39 MB  [k_lin -> k_final] (over dead VT)
  unsigned short* Vb  = (unsigned short*)(ws + 14761984);  // 8.39 MB  [k_qkv -> k_csv]
  unsigned short* fsab= (unsigned short*)(ws + 14761984);  // 8.39 MB  [k_lin -> k_final] (over dead Vb)
  unsigned short* pnum= (unsigned short*)(ws + 23150592);  // 16.78 MB [k_pv -> k_lin] (2 halves)
  float*          pden= (float*)(ws + 39927808);           // 0.26 MB  [k_pv -> k_lin]
  float*          bnst= (float*)(ws + 40189952);           // 1 KB

  k_prep  <<<160, 256, 0, stream>>>(w_q, w_k, w_v, w_l, wbq, wbk, wbv, wbl);
  k_qkv   <<<512, 256, 0, stream>>>(f_in, wbq, wbk, wbv, b_q, b_k, b_v, Qb, Kb, Vb);
  k_csv   <<<512, 256, 0, stream>>>(Qb, Kb, Vb, VT);
  k_pv    <<<512, 256, 0, stream>>>(Qb, Kb, VT, pnum, pden);
  k_lin   <<<512, 256, 0, stream>>>(f_in, pnum, pden, wbl, b_l, fsab, ybuf, part);
  k_bnred <<<128, 64, 0, stream>>>(part, gamma, beta, bnst);
  k_final <<<2048,256, 0, stream>>>(ybuf, fsab, bnst, out);
}

// Round 16
// 107.310 us; speedup vs baseline: 1.0126x; 1.0126x over previous
//
#include <hip/hip_runtime.h>
#include <stdint.h>

#define NB 16
#define NN 2048
#define ND 128
#define NH 32
#define NS (NB*NN)

typedef __attribute__((ext_vector_type(8))) short bf16x8;
typedef __attribute__((ext_vector_type(4))) float f32x4;
typedef __attribute__((ext_vector_type(16))) float f32x16;
typedef __attribute__((ext_vector_type(2))) int i32x2;

__device__ __forceinline__ unsigned short f2bf(float f){
  union { float f; unsigned int u; } v; v.f = f;
  unsigned int r = v.u + 0x7fffu + ((v.u >> 16) & 1u);
  return (unsigned short)(r >> 16);
}
__device__ __forceinline__ float bf2f(unsigned short u){
  union { unsigned int u; float f; } v; v.u = ((unsigned int)u) << 16;
  return v.f;
}
// raw 2^x (Q is pre-scaled by log2e, so exp(S) == exp2(S'))
__device__ __forceinline__ float fexp2(float x){
  float r; asm("v_exp_f32 %0, %1" : "=v"(r) : "v"(x)); return r;
}
// v_permlane32_swap_b32: after pswap(x,y): x = {x.lo, y.lo}, y = {x.hi, y.hi}
__device__ __forceinline__ void pswap(unsigned int &x, unsigned int &y){
#if __has_builtin(__builtin_amdgcn_permlane32_swap)
  i32x2 r = __builtin_amdgcn_permlane32_swap((int)x, (int)y, false, false);
  x = (unsigned int)r[0]; y = (unsigned int)r[1];
#else
  unsigned int sx = (unsigned int)__shfl_xor((int)x, 32, 64);
  unsigned int sy = (unsigned int)__shfl_xor((int)y, 32, 64);
  bool hi = ((threadIdx.x & 63) >> 5) != 0;
  unsigned int nx = hi ? sy : x;
  unsigned int ny = hi ? y  : sx;
  x = nx; y = ny;
#endif
}

// ---------------- k_prep: fp32 weights -> bf16 ----------------
__global__ __launch_bounds__(256) void k_prep(const float* wq, const float* wk, const float* wv, const float* wl,
                                              unsigned short* oq, unsigned short* ok, unsigned short* ov, unsigned short* ol){
  int i = blockIdx.x*256 + threadIdx.x;
  if (i < 4096) oq[i] = f2bf(wq[i]);
  else if (i < 8192) ok[i-4096] = f2bf(wk[i-4096]);
  else if (i < 24576) ov[i-8192] = f2bf(wv[i-8192]);
  else if (i < 40960) ol[i-24576] = f2bf(wl[i-24576]);
}

// ---------------- k_qkv: Q (scaled by log2e), K (S x 32), V (S x 128) in bf16 ----------------
__global__ __launch_bounds__(256) void k_qkv(const float* f, const unsigned short* wbq, const unsigned short* wbk,
                                             const unsigned short* wbv, const float* bq, const float* bk, const float* bv,
                                             unsigned short* Qb, unsigned short* Kb, unsigned short* Vb){
  int tid = threadIdx.x, wave = tid>>6, lane = tid&63, lr = lane&15, lg = lane>>4;
  long r0 = (long)blockIdx.x*64 + wave*16;
  bf16x8 a[4];
  const float4* frow4 = (const float4*)(f + (r0 + lr)*ND);
  #pragma unroll
  for (int ks=0; ks<4; ks++){
    int base = ks*8 + lg*2;
    float4 x0 = frow4[base], x1 = frow4[base+1];
    bf16x8 t;
    t[0]=(short)f2bf(x0.x); t[1]=(short)f2bf(x0.y); t[2]=(short)f2bf(x0.z); t[3]=(short)f2bf(x0.w);
    t[4]=(short)f2bf(x1.x); t[5]=(short)f2bf(x1.y); t[6]=(short)f2bf(x1.z); t[7]=(short)f2bf(x1.w);
    a[ks] = t;
  }
  #pragma unroll
  for (int cs=0; cs<12; cs++){
    const unsigned short* wsrc; const float* bsrc; int cl;
    if (cs<2){ wsrc=wbq; bsrc=bq; cl=cs*16; }
    else if (cs<4){ wsrc=wbk; bsrc=bk; cl=(cs-2)*16; }
    else { wsrc=wbv; bsrc=bv; cl=(cs-4)*16; }
    f32x4 acc = {0.f,0.f,0.f,0.f};
    #pragma unroll
    for (int ks=0;ks<4;ks++){
      bf16x8 b = *(const bf16x8*)(wsrc + (cl+lr)*ND + ks*32 + lg*8);
      acc = __builtin_amdgcn_mfma_f32_16x16x32_bf16(a[ks], b, acc, 0, 0, 0);
    }
    float bias = bsrc[cl + lr];
    #pragma unroll
    for (int r=0;r<4;r++){
      float v = acc[r] + bias;
      if (cs<2) v *= 1.4426950408889634f;   // fold log2(e) into Q
      long row = r0 + lg*4 + r;
      if (cs<2) Qb[row*NH + cl+lr] = f2bf(v);
      else if (cs<4) Kb[row*NH + cl+lr] = f2bf(v);
      else Vb[row*ND + cl+lr] = f2bf(v);
    }
  }
}

// ---------------- k_csv (R9-proven, verbatim): colsum + V' transpose/scale ----------------
// VT has 160 rows/batch: rows 0-127 = V^T * w (bf16), row 128 = w (bf16), rows 129-159 = 0.
__global__ __launch_bounds__(256) void k_csv(const unsigned short* Qb, const unsigned short* Kb,
                                             const unsigned short* Vb, unsigned short* VT){
  __shared__ unsigned short tr[128][65];
  __shared__ float wsh[64];
  __shared__ __align__(16) unsigned char qs[3][4096];
  int tid=threadIdx.x, wave=tid>>6, lane=tid&63, lr=lane&15, lg=lane>>4;
  int wg = (blockIdx.x & 7)*64 + (blockIdx.x >> 3);   // XCD-chunked swizzle (512 % 8 == 0)
  int b = wg >> 5;
  int m0 = (wg & 31)*64;
  const unsigned short* Qbb = Qb + (long)b*NN*NH;
  const unsigned short* Kbb = Kb + (long)b*NN*NH;
  const unsigned short* Vbb = Vb + ((long)b*NN + m0)*ND;

  auto stageQ = [&](int buf, int n0){
    int row = wave*16 + (lane>>2);      // 0..63
    int blk = lane & 3;
    int scol = (blk ^ ((row>>1)&3))*8;  // pre-swizzled source column (elems)
    __builtin_amdgcn_global_load_lds(
      (const __attribute__((address_space(1))) unsigned int*)(Qbb + (long)(n0+row)*NH + scol),
      (__attribute__((address_space(3))) unsigned int*)(&qs[buf][wave*1024]), 16, 0, 0);
  };

  // V loads early (consumed after the loop); drained by the first wait
  bf16x8 vreg[4];
  #pragma unroll
  for (int it=0; it<4; it++){
    int i = it*256 + tid;
    int r = i >> 4, c8 = (i & 15)*8;
    vreg[it] = *(const bf16x8*)(Vbb + r*ND + c8);
  }
  bf16x8 kf = *(const bf16x8*)(Kbb + (m0 + wave*16 + lr)*NH + lg*8);
  stageQ(0, 0);
  stageQ(1, 64);

  float csum = 0.f;
  int qrd = (lg ^ ((lr>>1)&3)) << 4;    // read blk offset (u-invariant)
  int qc = 0, qsn = 2;
  for (int it = 0; it < 32; ++it){
    if (it < 31) asm volatile("s_waitcnt vmcnt(1)" ::: "memory");
    else         asm volatile("s_waitcnt vmcnt(0)" ::: "memory");
    __builtin_amdgcn_s_barrier();
    if (it + 2 < 32) stageQ(qsn, (it+2)*64);
    asm volatile("" ::: "memory");
    #pragma unroll
    for (int u=0; u<4; u++){
      int r = u*16 + lr;
      bf16x8 qf = *(const bf16x8*)(&qs[qc][r*64 + qrd]);
      f32x4 c = {0.f,0.f,0.f,0.f};
      c = __builtin_amdgcn_mfma_f32_16x16x32_bf16(qf, kf, c, 0, 0, 0);
      csum += fexp2(c[0]) + fexp2(c[1]) + fexp2(c[2]) + fexp2(c[3]);
    }
    qc = (qc==2)?0:qc+1;
    qsn = (qsn==2)?0:qsn+1;
  }
  csum += __shfl_xor(csum, 16, 64);
  csum += __shfl_xor(csum, 32, 64);
  #pragma unroll
  for (int it=0; it<4; it++){
    int i = it*256 + tid;
    int r = i >> 4, c8 = (i & 15)*8;
    #pragma unroll
    for (int j=0;j<8;j++) tr[c8+j][r] = (unsigned short)vreg[it][j];
  }
  if (lg == 0) wsh[wave*16 + lr] = 1.f / csum;
  __syncthreads();
  unsigned short* VTb = VT + (long)b*160*NN;
  #pragma unroll
  for (int it=0; it<9; it++){
    int i = it*256 + tid;
    int e = i >> 4, m4 = (i & 15)*4;
    ushort4 o;
    if (e < 128){
      o.x = f2bf(bf2f(tr[e][m4+0]) * wsh[m4+0]);
      o.y = f2bf(bf2f(tr[e][m4+1]) * wsh[m4+1]);
      o.z = f2bf(bf2f(tr[e][m4+2]) * wsh[m4+2]);
      o.w = f2bf(bf2f(tr[e][m4+3]) * wsh[m4+3]);
    } else if (e == 128){
      o.x = f2bf(wsh[m4+0]); o.y = f2bf(wsh[m4+1]);
      o.z = f2bf(wsh[m4+2]); o.w = f2bf(wsh[m4+3]);
    } else { o.x = o.y = o.z = o.w = 0; }
    *(ushort4*)(VTb + (long)e*NN + m0 + m4) = o;
  }
  // zero-pad rows 144..159
  {
    int e = 144 + (tid >> 4), m4 = (tid & 15)*4;
    ushort4 z; z.x = z.y = z.z = z.w = 0;
    *(ushort4*)(VTb + (long)e*NN + m0 + m4) = z;
  }
}

// ---------------- k_pv: partial (E @ V', E @ w) over HALF the m-range ----------------
// R14-proven lean loop (inline SCORE->PV, K just-in-time, 2-buffer vts, counted vmcnt(5),
// NO launch_bounds min-waves hint — spills would corrupt counted vmcnt, R10-R12 lesson).
__global__ __launch_bounds__(256) void k_pv(const unsigned short* Qb, const unsigned short* Kb,
                                            const unsigned short* VT,
                                            unsigned short* pnum, float* pden){
  __shared__ __align__(16) unsigned char vts[2][20480];
  int tid=threadIdx.x, wave=tid>>6, lane=tid&63;
  int l31 = lane & 31, H = lane >> 5;
  int wg = (blockIdx.x & 7)*64 + (blockIdx.x >> 3);   // XCD-chunked swizzle (512 % 8 == 0)
  int half = wg & 1;
  int bq = wg >> 1;
  int b = bq >> 4;
  int q0 = (bq & 15)*128 + wave*32;
  int mbase = half*1024;
  const int NT = 16;
  const unsigned short* Qbb = Qb + (long)b*NN*NH;
  const unsigned short* Kbb = Kb + (long)b*NN*NH;
  const unsigned short* VTb = VT + (long)b*160*NN;

  auto stageV = [&](int buf, int m0c){
    #pragma unroll
    for (int t=0;t<5;t++){
      int i = wave*5 + t;                 // 0..19 row-groups of 8 -> 160 rows
      int e = i*8 + (lane>>3);
      int sblk = (lane&7) ^ (e&7);        // pre-swizzled source block
      __builtin_amdgcn_global_load_lds(
        (const __attribute__((address_space(1))) unsigned int*)(VTb + (long)e*NN + m0c + sblk*8),
        (__attribute__((address_space(3))) unsigned int*)(&vts[buf][i*1024]), 16, 0, 0);
    }
  };

  // qf loads FIRST (oldest in queue -> drained by the first counted wait)
  bf16x8 qf0 = *(const bf16x8*)(Qbb + (long)(q0 + l31)*NH + 8*H);
  bf16x8 qf1 = *(const bf16x8*)(Qbb + (long)(q0 + l31)*NH + 16 + 8*H);
  asm volatile("" ::: "memory");
  stageV(0, mbase);                       // V(0)
  asm volatile("" ::: "memory");

  f32x16 acc[5];
  #pragma unroll
  for (int c=0;c<5;c++)
    #pragma unroll
    for (int r=0;r<16;r++) acc[c][r] = 0.f;

  union U { unsigned int u[4]; bf16x8 v; };

  int cur = 0;
  for (int it = 0; it < NT; ++it){
    __builtin_amdgcn_s_barrier();          // all waves done reading vts[cur^1]
    // K(it) just-in-time (counts 4 in the vm queue)
    long mb = mbase + (long)it*64;
    bf16x8 k00 = *(const bf16x8*)(Kbb + (mb + l31)*NH + 8*H);
    bf16x8 k01 = *(const bf16x8*)(Kbb + (mb + l31)*NH + 16 + 8*H);
    bf16x8 k10 = *(const bf16x8*)(Kbb + (mb + 32 + l31)*NH + 8*H);
    bf16x8 k11 = *(const bf16x8*)(Kbb + (mb + 32 + l31)*NH + 16 + 8*H);
    asm volatile("" ::: "memory");
    if (it + 1 < NT) stageV(cur^1, mbase + (it+1)*64);
    asm volatile("" ::: "memory");
    if (it + 1 < NT) asm volatile("s_waitcnt vmcnt(5)" ::: "memory");  // V(it)+K(it) landed
    else             asm volatile("s_waitcnt vmcnt(0)" ::: "memory");
    __builtin_amdgcn_sched_barrier(0);
    const unsigned char* vcur = &vts[cur][0];

    #pragma unroll
    for (int t=0;t<2;t++){
      // score: S^T[m][q], m-subtile t (32 m-rows)
      f32x16 s;
      #pragma unroll
      for (int r=0;r<16;r++) s[r] = 0.f;
      s = __builtin_amdgcn_mfma_f32_32x32x16_bf16(t ? k10 : k00, qf0, s, 0, 0, 0);
      s = __builtin_amdgcn_mfma_f32_32x32x16_bf16(t ? k11 : k01, qf1, s, 0, 0, 0);
      #pragma unroll
      for (int r=0;r<16;r++) s[r] = fexp2(s[r]);
      // pack to bf16 pairs; cross-half exchange via permlane32_swap (pure VALU)
      unsigned int pk[8];
      #pragma unroll
      for (int p=0;p<8;p++)
        asm("v_cvt_pk_bf16_f32 %0, %1, %2" : "=v"(pk[p]) : "v"(s[2*p]), "v"(s[2*p+1]));
      pswap(pk[0], pk[2]);
      pswap(pk[1], pk[3]);
      pswap(pk[4], pk[6]);
      pswap(pk[5], pk[7]);
      // PV: acc[c] += E(32q x 16m) @ V'(16m x 32e), 2 k-steps x 5 e-tiles (c=4 -> den col 128)
      __builtin_amdgcn_s_setprio(1);
      #pragma unroll
      for (int ksl=0; ksl<2; ksl++){
        int KS = 2*t + ksl;
        U fa;
        #pragma unroll
        for (int i2=0;i2<4;i2++) fa.u[i2] = pk[ksl*4 + i2];
        #pragma unroll
        for (int c=0;c<5;c++){
          int e = c*32 + l31;
          bf16x8 vb = *(const bf16x8*)(vcur + (e<<7) + (((2*KS + H) ^ (e&7))<<4));
          acc[c] = __builtin_amdgcn_mfma_f32_32x32x16_bf16(fa.v, vb, acc[c], 0, 0, 0);
        }
      }
      __builtin_amdgcn_s_setprio(0);
    }
    cur ^= 1;
  }
  // write partials: numerator bf16; denominator f32 from acc[4] (V' col 128 = w, at l31==0)
  unsigned short* pn = pnum + (long)half*NS*ND + (long)b*NN*ND;
  float* pd = pden + (long)half*NS + (long)b*NN;
  #pragma unroll
  for (int r=0;r<16;r++){
    int rho = (r&3) + 8*(r>>2) + 4*H;
    long q = q0 + rho;
    #pragma unroll
    for (int c=0;c<4;c++)
      pn[q*ND + c*32 + l31] = f2bf(acc[c][r]);
    if (l31 == 0) pd[q] = acc[4][r];
  }
}

// ---------------- k_lin (R9-proven): fsa = (pn0+pn1)/(pd0+pd1) in-reg; y = (f - fsa) @ w_l^T + b_l ----------------
__global__ __launch_bounds__(256) void k_lin(const float* f, const unsigned short* pnum, const float* pden,
                                             const unsigned short* wbl, const float* bl,
                                             unsigned short* fsab, unsigned short* ybuf, float* part){
  __shared__ float psum[4][128], psq[4][128];
  int tid=threadIdx.x, wave=tid>>6, lane=tid&63, lr=lane&15, lg=lane>>4;
  long r0 = (long)blockIdx.x*64 + wave*16;
  long row = r0 + lr;
  float rinv = 1.f / (pden[row] + pden[NS + row]);
  bf16x8 a[4];
  {
    const float4* fr4 = (const float4*)(f + row*ND);
    const unsigned short* p0 = pnum + row*ND;
    const unsigned short* p1 = pnum + (long)NS*ND + row*ND;
    #pragma unroll
    for (int ks=0;ks<4;ks++){
      int c8 = ks*4 + lg;
      float4 x0 = fr4[c8*2], x1 = fr4[c8*2+1];
      bf16x8 v0 = *(const bf16x8*)(p0 + c8*8);
      bf16x8 v1 = *(const bf16x8*)(p1 + c8*8);
      float xf[8] = {x0.x,x0.y,x0.z,x0.w,x1.x,x1.y,x1.z,x1.w};
      bf16x8 t, fs;
      #pragma unroll
      for (int j=0;j<8;j++){
        float sa = (bf2f((unsigned short)v0[j]) + bf2f((unsigned short)v1[j])) * rinv;
        fs[j] = (short)f2bf(sa);
        t[j] = (short)f2bf(xf[j] - bf2f((unsigned short)fs[j]));
      }
      a[ks] = t;
      *(bf16x8*)(fsab + row*ND + c8*8) = fs;
    }
  }
  #pragma unroll
  for (int cs=0;cs<8;cs++){
    f32x4 acc = {0.f,0.f,0.f,0.f};
    #pragma unroll
    for (int ks=0;ks<4;ks++){
      bf16x8 bfr = *(const bf16x8*)(wbl + (cs*16+lr)*ND + ks*32 + lg*8);
      acc = __builtin_amdgcn_mfma_f32_16x16x32_bf16(a[ks], bfr, acc, 0, 0, 0);
    }
    float bias = bl[cs*16+lr];
    float l1=0.f, l2=0.f;
    #pragma unroll
    for (int r=0;r<4;r++){
      float y = acc[r] + bias;
      ybuf[(r0 + lg*4 + r)*ND + cs*16 + lr] = f2bf(y);
      l1 += y; l2 += y*y;
    }
    l1 += __shfl_xor(l1,16,64); l1 += __shfl_xor(l1,32,64);
    l2 += __shfl_xor(l2,16,64); l2 += __shfl_xor(l2,32,64);
    if (lg==0){ psum[wave][cs*16+lr] = l1; psq[wave][cs*16+lr] = l2; }
  }
  __syncthreads();
  if (tid < 128){
    float t1 = psum[0][tid]+psum[1][tid]+psum[2][tid]+psum[3][tid];
    float t2 = psq[0][tid]+psq[1][tid]+psq[2][tid]+psq[3][tid];
    part[tid*512 + blockIdx.x] = t1;
    part[65536 + tid*512 + blockIdx.x] = t2;
  }
}

// ---------------- k_bnred: per-channel reduction -> BN scale/shift ----------------
__global__ __launch_bounds__(64) void k_bnred(const float* part, const float* gamma, const float* beta, float* bnstat){
  int c = blockIdx.x, t = threadIdx.x;
  float s=0.f, q=0.f;
  for (int i=t; i<512; i+=64){ s += part[c*512+i]; q += part[65536 + c*512+i]; }
  #pragma unroll
  for (int m=1; m<64; m<<=1){ s += __shfl_xor(s,m,64); q += __shfl_xor(q,m,64); }
  if (t==0){
    float mean = s * (1.f/(float)NS);
    float var  = q * (1.f/(float)NS) - mean*mean;
    float rstd = rsqrtf(var + 1e-5f);
    float sc = gamma[c]*rstd;
    bnstat[c] = sc;
    bnstat[128+c] = beta[c] - mean*sc;
  }
}

// ---------------- k_final: out = relu(y*scale + shift) + fsa ----------------
__global__ __launch_bounds__(256) void k_final(const unsigned short* ybuf, const unsigned short* fsab, const float* bnstat,
                                               float* out){
  long i0 = ((long)blockIdx.x*256 + threadIdx.x)*8;
  int c0 = (int)(i0 & (ND-1));
  bf16x8 yv = *(const bf16x8*)(ybuf + i0);
  bf16x8 fv = *(const bf16x8*)(fsab + i0);
  f32x4 o0, o1;
  #pragma unroll
  for (int j=0;j<8;j++){
    int c = c0 + j;
    float v = bf2f((unsigned short)yv[j]) * bnstat[c] + bnstat[128+c];
    v = v > 0.f ? v : 0.f;
    float r = v + bf2f((unsigned short)fv[j]);
    if (j<4) o0[j] = r; else o1[j-4] = r;
  }
  *(f32x4*)(out + i0) = o0;
  *(f32x4*)(out + i0 + 4) = o1;
}

extern "C" void kernel_launch(void* const* d_in, const int* in_sizes, int n_in,
                              void* d_out, int out_size, void* d_ws, size_t ws_size,
                              hipStream_t stream){
  const float* f_in  = (const float*)d_in[0];
  const float* w_q   = (const float*)d_in[1];
  const float* b_q   = (const float*)d_in[2];
  const float* w_k   = (const float*)d_in[3];
  const float* b_k   = (const float*)d_in[4];
  const float* w_v   = (const float*)d_in[5];
  const float* b_v   = (const float*)d_in[6];
  const float* w_l   = (const float*)d_in[7];
  const float* b_l   = (const float*)d_in[8];
  const float* gamma = (const float*)d_in[9];
  const float* beta  = (const float*)d_in[10];
  float* out = (float*)d_out;
  char* ws = (char*)d_ws;

  // ws layout (peak ~40.2 MB; overlays annotated by liveness)
  unsigned short* wbq = (unsigned short*)(ws + 0);
  unsigned short* wbk = (unsigned short*)(ws + 8192);
  unsigned short* wbv = (unsigned short*)(ws + 16384);
  unsigned short* wbl = (unsigned short*)(ws + 49152);
  unsigned short* Qb  = (unsigned short*)(ws + 81920);     // 2 MB     [k_qkv -> k_pv]
  float*          part= (float*)(ws + 81920);              // 0.52 MB  [k_lin -> k_bnred] (over dead Qb)
  unsigned short* Kb  = (unsigned short*)(ws + 2179072);   // 2 MB     [k_qkv -> k_pv]
  unsigned short* VT  = (unsigned short*)(ws + 4276224);   // 10.49 MB [k_csv -> k_pv] (160 rows/batch)
  unsigned short* ybuf= (unsigned short*)(ws + 4276224);   // 8.39 MB  [k_lin -> k_final] (over dead VT)
  unsigned short* Vb  = (unsigned short*)(ws + 14761984);  // 8.39 MB  [k_qkv -> k_csv]
  unsigned short* fsab= (unsigned short*)(ws + 14761984);  // 8.39 MB  [k_lin -> k_final] (over dead Vb)
  unsigned short* pnum= (unsigned short*)(ws + 23150592);  // 16.78 MB [k_pv -> k_lin] (2 halves)
  float*          pden= (float*)(ws + 39927808);           // 0.26 MB  [k_pv -> k_lin]
  float*          bnst= (float*)(ws + 40189952);           // 1 KB

  k_prep  <<<160, 256, 0, stream>>>(w_q, w_k, w_v, w_l, wbq, wbk, wbv, wbl);
  k_qkv   <<<512, 256, 0, stream>>>(f_in, wbq, wbk, wbv, b_q, b_k, b_v, Qb, Kb, Vb);
  k_csv   <<<512, 256, 0, stream>>>(Qb, Kb, Vb, VT);
  k_pv    <<<512, 256, 0, stream>>>(Qb, Kb, VT, pnum, pden);
  k_lin   <<<512, 256, 0, stream>>>(f_in, pnum, pden, wbl, b_l, fsab, ybuf, part);
  k_bnred <<<128, 64, 0, stream>>>(part, gamma, beta, bnst);
  k_final <<<2048,256, 0, stream>>>(ybuf, fsab, bnst, out);
}